// Round 5
// baseline (309.401 us; speedup 1.0000x reference)
//
#include <hip/hip_runtime.h>
#include <hip/hip_bf16.h>
#include <stdint.h>

#define Bx 4
#define Tx 2048
#define Cx 1024
#define Hx 16
#define Dx 64
#define Mx (Bx*Tx)

typedef __bf16 bf16x8 __attribute__((ext_vector_type(8)));
typedef float f32x4 __attribute__((ext_vector_type(4)));
typedef unsigned short u16x8 __attribute__((ext_vector_type(8)));

__device__ __forceinline__ unsigned short f2bf(float f) {
  union { float f; unsigned u; } v; v.f = f;
  unsigned r = v.u + 0x7fffu + ((v.u >> 16) & 1u);
  return (unsigned short)(r >> 16);
}

// ---------------- f32 -> bf16 convert (vectorized, 8 elems/thread) -------------
__global__ void cvt_kernel(const float* __restrict__ in, unsigned short* __restrict__ out, int n) {
  int i = blockIdx.x * blockDim.x + threadIdx.x;
  int idx = i << 3;
  if (idx >= n) return;
  const float4* p = (const float4*)(in + idx);
  float4 a = p[0], b = p[1];
  u16x8 o;
  o[0] = f2bf(a.x); o[1] = f2bf(a.y); o[2] = f2bf(a.z); o[3] = f2bf(a.w);
  o[4] = f2bf(b.x); o[5] = f2bf(b.y); o[6] = f2bf(b.z); o[7] = f2bf(b.w);
  *(u16x8*)(out + idx) = o;
}

#define GLOAD_LDS16(g, l) \
  __builtin_amdgcn_global_load_lds((const __attribute__((address_space(1))) void*)(g), \
                                   (__attribute__((address_space(3))) void*)(l), 16, 0, 0)

// ---------------- depth-2 pipelined NT GEMM --------------------------------------
// C[M][N] = A[M][K] * B[N][K]^T, bf16 in, f32 acc. BM=256 BN=128 BK=64,
// 512 thr = 8 waves (4M x 2N), per-wave 64x64 out. LDS 144KB TRIPLE-buffered.
// Pipeline: during tile t, stage tile t+2. At tile-t top: s_waitcnt vmcnt(6)
// (the 6 newest = tile t+1's loads; all of tile t's are older -> landed).
// vmcnt never drains to 0 until the last tile; loads get ~2 K-tiles of MFMA
// to cover HBM latency. ONE barrier per K-tile.
// Race proof: buf[(t+2)%3]'s last reader is tile t-1; every wave finishes
// tile t-1 (lgkm-complete before its MFMAs) before reaching barrier t;
// staging for t+2 is issued only after barrier t. DMA writes land after issue.
// T2: linear LDS dest + inverse-swizzled global source chunk (c ^ (row&7)),
//     same XOR on ds_read -> 2-way (free) bank access.
// T5: setprio(1) around each 16-MFMA cluster.
template<int OUT_F32>
__global__ __launch_bounds__(512, 1) void gemm8p(const unsigned short* __restrict__ A,
                                                 const unsigned short* __restrict__ Bm,
                                                 void* __restrict__ Cv,
                                                 int M, int N, int K)
{
  __shared__ unsigned short As[3][256 * 64];   // 96 KB
  __shared__ unsigned short Bs[3][128 * 64];   // 48 KB
  const int tid = threadIdx.x;
  const int wave = tid >> 6, lane = tid & 63;
  const int l15 = lane & 15, l4 = lane >> 4;
  const int wm = wave >> 1, wn = wave & 1;
  const int NB = N >> 7;
  // T1: bijective XCD swizzle (gridDim.x % 8 == 0 at both call sites)
  const int cpx = (int)gridDim.x >> 3;
  const int bid = (int)blockIdx.x;
  const int swz = (bid & 7) * cpx + (bid >> 3);
  const int bx = swz % NB, by = swz / NB;
  const int mBase = by << 8, nBase = bx << 7;

  const int srow   = tid >> 3;                  // row 0..63 within a 64-row stage
  const int schunk = (tid & 7) ^ (srow & 7);    // inverse-swizzled source chunk
  const unsigned short* aSrc = A  + (size_t)(mBase + srow) * K + (schunk << 3);
  const unsigned short* bSrc = Bm + (size_t)(nBase + srow) * K + (schunk << 3);
  const int dstOff = wave << 9;                 // wave-uniform lane-linear dest

  f32x4 acc[4][4];
  #pragma unroll
  for (int i = 0; i < 4; ++i)
    #pragma unroll
    for (int j = 0; j < 4; ++j) { acc[i][j][0]=0.f; acc[i][j][1]=0.f; acc[i][j][2]=0.f; acc[i][j][3]=0.f; }

  const int NT = K >> 6;
  const int s7 = l15 & 7;

  // stage lines: A has 4 (rows +0,+64,+128,+192), B has 2 (rows +0,+64)
#define STG_A(k0, dst, j)  GLOAD_LDS16(aSrc + (size_t)(64*(j))*K + (k0), (dst) + 4096*(j) + dstOff)
#define STG_B(k0, dst, j)  GLOAD_LDS16(bSrc + (size_t)(64*(j))*K + (k0), (dst) + 4096*(j) + dstOff)

  // prologue: tiles 0 and 1
  STG_A(0, As[0], 0); STG_A(0, As[0], 1); STG_A(0, As[0], 2); STG_A(0, As[0], 3);
  STG_B(0, Bs[0], 0); STG_B(0, Bs[0], 1);
  STG_A(64, As[1], 0); STG_A(64, As[1], 1); STG_A(64, As[1], 2); STG_A(64, As[1], 3);
  STG_B(64, Bs[1], 0); STG_B(64, Bs[1], 1);

  int bufR = 0;
  for (int t = 0; t < NT; ++t) {
    if (t + 1 < NT) asm volatile("s_waitcnt vmcnt(6)" ::: "memory");  // tile t landed
    else            asm volatile("s_waitcnt vmcnt(0)" ::: "memory");
    __builtin_amdgcn_s_barrier();
    asm volatile("" ::: "memory");

    const unsigned short* curA = As[bufR];
    const unsigned short* curB = Bs[bufR];
    int bufS = bufR + 2; if (bufS >= 3) bufS -= 3;
    unsigned short* sA = As[bufS];
    unsigned short* sB = Bs[bufS];
    const bool doStage = (t + 2 < NT);
    const int k2 = (t + 2) << 6;

    // ---- phase 0: stage 3, ds_read kk=0 frags, 16 MFMA ----
    if (doStage) { STG_A(k2, sA, 0); STG_A(k2, sA, 1); STG_A(k2, sA, 2); }
    {
      const int ch = l4 ^ s7;
      bf16x8 af[4], bfr[4];
      #pragma unroll
      for (int mi = 0; mi < 4; ++mi)
        af[mi]  = *(const bf16x8*)&curA[((wm << 6) + (mi << 4) + l15) * 64 + (ch << 3)];
      #pragma unroll
      for (int nj = 0; nj < 4; ++nj)
        bfr[nj] = *(const bf16x8*)&curB[((wn << 6) + (nj << 4) + l15) * 64 + (ch << 3)];
      __builtin_amdgcn_s_setprio(1);
      #pragma unroll
      for (int mi = 0; mi < 4; ++mi)
        #pragma unroll
        for (int nj = 0; nj < 4; ++nj)
          acc[mi][nj] = __builtin_amdgcn_mfma_f32_16x16x32_bf16(af[mi], bfr[nj], acc[mi][nj], 0, 0, 0);
      __builtin_amdgcn_s_setprio(0);
    }
    // ---- phase 1: stage 3, ds_read kk=1 frags, 16 MFMA ----
    if (doStage) { STG_A(k2, sA, 3); STG_B(k2, sB, 0); STG_B(k2, sB, 1); }
    {
      const int ch = (4 | l4) ^ s7;
      bf16x8 af[4], bfr[4];
      #pragma unroll
      for (int mi = 0; mi < 4; ++mi)
        af[mi]  = *(const bf16x8*)&curA[((wm << 6) + (mi << 4) + l15) * 64 + (ch << 3)];
      #pragma unroll
      for (int nj = 0; nj < 4; ++nj)
        bfr[nj] = *(const bf16x8*)&curB[((wn << 6) + (nj << 4) + l15) * 64 + (ch << 3)];
      __builtin_amdgcn_s_setprio(1);
      #pragma unroll
      for (int mi = 0; mi < 4; ++mi)
        #pragma unroll
        for (int nj = 0; nj < 4; ++nj)
          acc[mi][nj] = __builtin_amdgcn_mfma_f32_16x16x32_bf16(af[mi], bfr[nj], acc[mi][nj], 0, 0, 0);
      __builtin_amdgcn_s_setprio(0);
    }
    asm volatile("" ::: "memory");
    bufR = (bufR == 2) ? 0 : bufR + 1;
  }
#undef STG_A
#undef STG_B

  #pragma unroll
  for (int mi = 0; mi < 4; ++mi)
    #pragma unroll
    for (int nj = 0; nj < 4; ++nj) {
      const int row = mBase + (wm << 6) + (mi << 4) + (l4 << 2);
      const int col = nBase + (wn << 6) + (nj << 4) + l15;
      #pragma unroll
      for (int r = 0; r < 4; ++r) {
        float v = acc[mi][nj][r];
        if (OUT_F32) ((float*)Cv)[(size_t)(row + r) * N + col] = v;
        else ((unsigned short*)Cv)[(size_t)(row + r) * N + col] = f2bf(v);
      }
    }
}

// ---------------- V transpose: qkv[...,2048+h*64+d] -> vt[b,h,d,t] ---------------
__global__ void vtrans_kernel(const unsigned short* __restrict__ qkv, unsigned short* __restrict__ vt) {
  const int bh = blockIdx.y;
  const int b = bh >> 4, h = bh & 15;
  const int t0 = blockIdx.x << 6;
  __shared__ unsigned short tile[64][65];
  const int tid = threadIdx.x;
  const unsigned short* src = qkv + (size_t)b * Tx * 3072 + 2048 + h * 64;
  for (int e = tid; e < 4096; e += 256) {
    int r = e >> 6, c = e & 63;
    tile[c][r] = src[(size_t)(t0 + r) * 3072 + c];
  }
  __syncthreads();
  unsigned short* dst = vt + (size_t)bh * 64 * Tx + t0;
  for (int e = tid; e < 4096; e += 256) {
    int d = e >> 6, tt = e & 63;
    dst[(size_t)d * Tx + tt] = tile[d][tt];
  }
}

// ---------------- causal flash attention v3 (unchanged) ---------------------------
__device__ __forceinline__ void compute_half(
    const unsigned short* __restrict__ Ks, const unsigned short* __restrict__ Vs,
    unsigned short* __restrict__ Plw,
    bf16x8 aq0, bf16x8 aq1, float* m_run, float* rs, f32x4* oacc,
    int qrow0, int kv0, bool diag, int l15, int l4)
{
  const float SC = 0.125f * 1.44269504f;
  f32x4 s[4];
  #pragma unroll
  for (int nt = 0; nt < 4; ++nt) { s[nt][0]=0.f; s[nt][1]=0.f; s[nt][2]=0.f; s[nt][3]=0.f; }
  #pragma unroll
  for (int nt = 0; nt < 4; ++nt) {
    const int r = (nt << 4) + l15, sz = r & 7;
    bf16x8 bk0 = *(const bf16x8*)&Ks[r * 64 + ((l4 ^ sz) << 3)];
    bf16x8 bk1 = *(const bf16x8*)&Ks[r * 64 + (((l4 + 4) ^ sz) << 3)];
    s[nt] = __builtin_amdgcn_mfma_f32_16x16x32_bf16(aq0, bk0, s[nt], 0, 0, 0);
    s[nt] = __builtin_amdgcn_mfma_f32_16x16x32_bf16(aq1, bk1, s[nt], 0, 0, 0);
  }
  #pragma unroll
  for (int nt = 0; nt < 4; ++nt) {
    const int kv = kv0 + (nt << 4) + l15;
    #pragma unroll
    for (int r = 0; r < 4; ++r) {
      float val = s[nt][r] * SC;
      if (diag && kv > qrow0 + (l4 << 2) + r) val = -3.0e38f;
      s[nt][r] = val;
    }
  }
  float pm[4];
  #pragma unroll
  for (int r = 0; r < 4; ++r)
    pm[r] = fmaxf(fmaxf(s[0][r], s[1][r]), fmaxf(s[2][r], s[3][r]));
  int ok = (pm[0] <= m_run[0] + 8.f) & (pm[1] <= m_run[1] + 8.f)
         & (pm[2] <= m_run[2] + 8.f) & (pm[3] <= m_run[3] + 8.f);
  if (!__all(ok)) {
    #pragma unroll
    for (int off = 1; off < 16; off <<= 1)
      #pragma unroll
      for (int r = 0; r < 4; ++r) pm[r] = fmaxf(pm[r], __shfl_xor(pm[r], off));
    #pragma unroll
    for (int r = 0; r < 4; ++r) {
      float mnew = fmaxf(m_run[r], pm[r]);
      float corr = exp2f(m_run[r] - mnew);
      rs[r] *= corr;
      #pragma unroll
      for (int nt = 0; nt < 4; ++nt) oacc[nt][r] *= corr;
      m_run[r] = mnew;
    }
  }
  #pragma unroll
  for (int nt = 0; nt < 4; ++nt)
    #pragma unroll
    for (int r = 0; r < 4; ++r) {
      float p = exp2f(s[nt][r] - m_run[r]);
      s[nt][r] = p;
      rs[r] += p;
    }
  #pragma unroll
  for (int nt = 0; nt < 4; ++nt)
    #pragma unroll
    for (int r = 0; r < 4; ++r)
      Plw[((l4 << 2) + r) * 72 + (nt << 4) + l15] = f2bf(s[nt][r]);
  asm volatile("s_waitcnt lgkmcnt(0)" ::: "memory");
  __builtin_amdgcn_sched_barrier(0);
  bf16x8 ap0 = *(const bf16x8*)&Plw[l15 * 72 + (l4 << 3)];
  bf16x8 ap1 = *(const bf16x8*)&Plw[l15 * 72 + 32 + (l4 << 3)];
  #pragma unroll
  for (int nt = 0; nt < 4; ++nt) {
    const int r = (nt << 4) + l15, vz = r & 7;
    bf16x8 bv0 = *(const bf16x8*)&Vs[r * 64 + ((l4 ^ vz) << 3)];
    bf16x8 bv1 = *(const bf16x8*)&Vs[r * 64 + (((l4 + 4) ^ vz) << 3)];
    oacc[nt] = __builtin_amdgcn_mfma_f32_16x16x32_bf16(ap0, bv0, oacc[nt], 0, 0, 0);
    oacc[nt] = __builtin_amdgcn_mfma_f32_16x16x32_bf16(ap1, bv1, oacc[nt], 0, 0, 0);
  }
}

__global__ __launch_bounds__(256, 4) void attn_kernel(const unsigned short* __restrict__ qkv,
                                                      const unsigned short* __restrict__ vt,
                                                      unsigned short* __restrict__ aout)
{
  const int id = blockIdx.x;
  const int xcd = id & 7, sblk = id >> 3;
  const int xblk = sblk & 15;
  const int bh = (xcd << 3) + (sblk >> 4);
  const int b = bh >> 4, h = bh & 15;
  const int wave = threadIdx.x >> 6, lane = threadIdx.x & 63;
  const int l15 = lane & 15, l4 = lane >> 4;
  const int qi0 = (xblk << 2) + wave;

  const unsigned short* qp = qkv + (size_t)b * Tx * 3072 + h * 64;
  const unsigned short* kp = qp + 1024;
  const unsigned short* vp = vt + (size_t)bh * 64 * Tx;
  unsigned short* op = aout + (size_t)b * Tx * 1024 + h * 64;

  __shared__ unsigned short Ks[64 * 64];
  __shared__ unsigned short Vs[64 * 64];
  __shared__ unsigned short Pl[4][2][16 * 72];

  const int qiA = qi0, qiB = 127 - qi0;
  const int qrA = qiA << 4, qrB = qiB << 4;
  const int lastA = xblk, lastB = 31 - xblk;

  bf16x8 aqA0 = *(const bf16x8*)&qp[(size_t)(qrA + l15) * 3072 + (l4 << 3)];
  bf16x8 aqA1 = *(const bf16x8*)&qp[(size_t)(qrA + l15) * 3072 + 32 + (l4 << 3)];
  bf16x8 aqB0 = *(const bf16x8*)&qp[(size_t)(qrB + l15) * 3072 + (l4 << 3)];
  bf16x8 aqB1 = *(const bf16x8*)&qp[(size_t)(qrB + l15) * 3072 + 32 + (l4 << 3)];

  float mA[4], rsA[4], mB[4], rsB[4];
  f32x4 oA[4], oB[4];
  #pragma unroll
  for (int r = 0; r < 4; ++r) { mA[r]=0.f; rsA[r]=0.f; mB[r]=0.f; rsB[r]=0.f; }
  #pragma unroll
  for (int nt = 0; nt < 4; ++nt) {
    oA[nt][0]=0.f; oA[nt][1]=0.f; oA[nt][2]=0.f; oA[nt][3]=0.f;
    oB[nt][0]=0.f; oB[nt][1]=0.f; oB[nt][2]=0.f; oB[nt][3]=0.f;
  }

  const int srw = lane >> 3;
  const int sj  = (lane & 7) ^ srw;

  for (int kvt = 0; kvt <= lastB; ++kvt) {
    const int kv0 = kvt << 6;
    {
      const int c0 = wave << 1, c1 = c0 + 1;
      const int r0 = (c0 << 3) + srw, r1 = (c1 << 3) + srw;
      GLOAD_LDS16(kp + (size_t)(kv0 + r0) * 3072 + (sj << 3), Ks + (c0 << 9));
      GLOAD_LDS16(kp + (size_t)(kv0 + r1) * 3072 + (sj << 3), Ks + (c1 << 9));
      GLOAD_LDS16(vp + (size_t)r0 * 2048 + kv0 + (sj << 3),   Vs + (c0 << 9));
      GLOAD_LDS16(vp + (size_t)r1 * 2048 + kv0 + (sj << 3),   Vs + (c1 << 9));
    }
    __syncthreads();

    compute_half(Ks, Vs, Pl[wave][1], aqB0, aqB1, mB, rsB, oB, qrB, kv0, kvt == lastB, l15, l4);
    if (kvt <= lastA)
      compute_half(Ks, Vs, Pl[wave][0], aqA0, aqA1, mA, rsA, oA, qrA, kv0, kvt == lastA, l15, l4);

    __syncthreads();
  }

  #pragma unroll
  for (int off = 1; off < 16; off <<= 1)
    #pragma unroll
    for (int r = 0; r < 4; ++r) { rsA[r] += __shfl_xor(rsA[r], off); rsB[r] += __shfl_xor(rsB[r], off); }
  #pragma unroll
  for (int r = 0; r < 4; ++r) {
    const float invA = 1.0f / rsA[r], invB = 1.0f / rsB[r];
    #pragma unroll
    for (int nt = 0; nt < 4; ++nt) {
      op[(size_t)(qrA + (l4 << 2) + r) * 1024 + (nt << 4) + l15] = f2bf(oA[nt][r] * invA);
      op[(size_t)(qrB + (l4 << 2) + r) * 1024 + (nt << 4) + l15] = f2bf(oB[nt][r] * invB);
    }
  }
}

// ---------------- launch ----------------------------------------------------------
extern "C" void kernel_launch(void* const* d_in, const int* in_sizes, int n_in,
                              void* d_out, int out_size, void* d_ws, size_t ws_size,
                              hipStream_t stream) {
  const float* x     = (const float*)d_in[0];
  const float* wqkv  = (const float*)d_in[1];
  const float* wproj = (const float*)d_in[2];

  char* ws = (char*)d_ws;
  unsigned short* qkvb = (unsigned short*)(ws);
  unsigned short* vtb  = (unsigned short*)(ws + 50331648);
  unsigned short* xb   = (unsigned short*)(ws + 50331648 + 16777216);
  unsigned short* wqb  = (unsigned short*)(ws + 50331648 + 16777216 + 16777216);
  unsigned short* wpb  = (unsigned short*)(ws + 50331648 + 16777216 + 16777216 + 6291456);
  unsigned short* aob  = xb;  // alias: xb dead after GEMM1

  cvt_kernel<<<4096, 256, 0, stream>>>(x,     xb,  Bx * Tx * Cx);
  cvt_kernel<<<1536, 256, 0, stream>>>(wqkv,  wqb, 3 * Cx * Cx);
  cvt_kernel<<<512,  256, 0, stream>>>(wproj, wpb, Cx * Cx);

  gemm8p<0><<<dim3(768), 512, 0, stream>>>(xb, wqb, qkvb, Mx, 3072, 1024);
  vtrans_kernel<<<dim3(32, 64), 256, 0, stream>>>(qkvb, vtb);
  attn_kernel<<<1024, 256, 0, stream>>>(qkvb, vtb, aob);
  gemm8p<1><<<dim3(256), 512, 0, stream>>>(aob, wpb, d_out, Mx, 1024, 1024);
}

// Round 7
// 275.201 us; speedup vs baseline: 1.1243x; 1.1243x over previous
//
#include <hip/hip_runtime.h>
#include <hip/hip_bf16.h>
#include <stdint.h>

#define Bx 4
#define Tx 2048
#define Cx 1024
#define Hx 16
#define Dx 64
#define Mx (Bx*Tx)

typedef __bf16 bf16x8 __attribute__((ext_vector_type(8)));
typedef float f32x4 __attribute__((ext_vector_type(4)));
typedef unsigned short u16x8 __attribute__((ext_vector_type(8)));

__device__ __forceinline__ unsigned short f2bf(float f) {
  union { float f; unsigned u; } v; v.f = f;
  unsigned r = v.u + 0x7fffu + ((v.u >> 16) & 1u);
  return (unsigned short)(r >> 16);
}

__device__ __forceinline__ unsigned cvt_pk_bf16(float a, float b) {
  unsigned r;
  asm("v_cvt_pk_bf16_f32 %0, %1, %2" : "=v"(r) : "v"(a), "v"(b));
  return r;  // low16 = bf16(a), high16 = bf16(b)
}

// ---------------- fused f32 -> bf16 convert for all three inputs ----------------
__global__ void cvt3_kernel(const float* __restrict__ x, const float* __restrict__ wq,
                            const float* __restrict__ wp,
                            unsigned short* __restrict__ xb, unsigned short* __restrict__ wqb,
                            unsigned short* __restrict__ wpb) {
  const int n1 = Bx * Tx * Cx;            // 8388608
  const int n2 = 3 * Cx * Cx;             // 3145728
  int idx = (blockIdx.x * blockDim.x + threadIdx.x) << 3;
  const float* src; unsigned short* dst; int off;
  if (idx < n1)            { src = x;  dst = xb;  off = idx; }
  else if (idx < n1 + n2)  { src = wq; dst = wqb; off = idx - n1; }
  else                     { src = wp; dst = wpb; off = idx - n1 - n2; }
  const float4* p = (const float4*)(src + off);
  float4 a = p[0], b = p[1];
  u16x8 o;
  o[0] = f2bf(a.x); o[1] = f2bf(a.y); o[2] = f2bf(a.z); o[3] = f2bf(a.w);
  o[4] = f2bf(b.x); o[5] = f2bf(b.y); o[6] = f2bf(b.z); o[7] = f2bf(b.w);
  *(u16x8*)(dst + off) = o;
}

#define GLOAD_LDS16(g, l) \
  __builtin_amdgcn_global_load_lds((const __attribute__((address_space(1))) void*)(g), \
                                   (__attribute__((address_space(3))) void*)(l), 16, 0, 0)

// ---------------- depth-2 pipelined NT GEMM (unchanged from R5) -------------------
template<int OUT_F32>
__global__ __launch_bounds__(512, 1) void gemm8p(const unsigned short* __restrict__ A,
                                                 const unsigned short* __restrict__ Bm,
                                                 void* __restrict__ Cv,
                                                 int M, int N, int K)
{
  __shared__ unsigned short As[3][256 * 64];
  __shared__ unsigned short Bs[3][128 * 64];
  const int tid = threadIdx.x;
  const int wave = tid >> 6, lane = tid & 63;
  const int l15 = lane & 15, l4 = lane >> 4;
  const int wm = wave >> 1, wn = wave & 1;
  const int NB = N >> 7;
  const int cpx = (int)gridDim.x >> 3;
  const int bid = (int)blockIdx.x;
  const int swz = (bid & 7) * cpx + (bid >> 3);
  const int bx = swz % NB, by = swz / NB;
  const int mBase = by << 8, nBase = bx << 7;

  const int srow   = tid >> 3;
  const int schunk = (tid & 7) ^ (srow & 7);
  const unsigned short* aSrc = A  + (size_t)(mBase + srow) * K + (schunk << 3);
  const unsigned short* bSrc = Bm + (size_t)(nBase + srow) * K + (schunk << 3);
  const int dstOff = wave << 9;

  f32x4 acc[4][4];
  #pragma unroll
  for (int i = 0; i < 4; ++i)
    #pragma unroll
    for (int j = 0; j < 4; ++j) { acc[i][j][0]=0.f; acc[i][j][1]=0.f; acc[i][j][2]=0.f; acc[i][j][3]=0.f; }

  const int NT = K >> 6;
  const int s7 = l15 & 7;

#define STG_A(k0, dst, j)  GLOAD_LDS16(aSrc + (size_t)(64*(j))*K + (k0), (dst) + 4096*(j) + dstOff)
#define STG_B(k0, dst, j)  GLOAD_LDS16(bSrc + (size_t)(64*(j))*K + (k0), (dst) + 4096*(j) + dstOff)

  STG_A(0, As[0], 0); STG_A(0, As[0], 1); STG_A(0, As[0], 2); STG_A(0, As[0], 3);
  STG_B(0, Bs[0], 0); STG_B(0, Bs[0], 1);
  STG_A(64, As[1], 0); STG_A(64, As[1], 1); STG_A(64, As[1], 2); STG_A(64, As[1], 3);
  STG_B(64, Bs[1], 0); STG_B(64, Bs[1], 1);

  int bufR = 0;
  for (int t = 0; t < NT; ++t) {
    if (t + 1 < NT) asm volatile("s_waitcnt vmcnt(6)" ::: "memory");
    else            asm volatile("s_waitcnt vmcnt(0)" ::: "memory");
    __builtin_amdgcn_s_barrier();
    asm volatile("" ::: "memory");

    const unsigned short* curA = As[bufR];
    const unsigned short* curB = Bs[bufR];
    int bufS = bufR + 2; if (bufS >= 3) bufS -= 3;
    unsigned short* sA = As[bufS];
    unsigned short* sB = Bs[bufS];
    const bool doStage = (t + 2 < NT);
    const int k2 = (t + 2) << 6;

    if (doStage) { STG_A(k2, sA, 0); STG_A(k2, sA, 1); STG_A(k2, sA, 2); }
    {
      const int ch = l4 ^ s7;
      bf16x8 af[4], bfr[4];
      #pragma unroll
      for (int mi = 0; mi < 4; ++mi)
        af[mi]  = *(const bf16x8*)&curA[((wm << 6) + (mi << 4) + l15) * 64 + (ch << 3)];
      #pragma unroll
      for (int nj = 0; nj < 4; ++nj)
        bfr[nj] = *(const bf16x8*)&curB[((wn << 6) + (nj << 4) + l15) * 64 + (ch << 3)];
      __builtin_amdgcn_s_setprio(1);
      #pragma unroll
      for (int mi = 0; mi < 4; ++mi)
        #pragma unroll
        for (int nj = 0; nj < 4; ++nj)
          acc[mi][nj] = __builtin_amdgcn_mfma_f32_16x16x32_bf16(af[mi], bfr[nj], acc[mi][nj], 0, 0, 0);
      __builtin_amdgcn_s_setprio(0);
    }
    if (doStage) { STG_A(k2, sA, 3); STG_B(k2, sB, 0); STG_B(k2, sB, 1); }
    {
      const int ch = (4 | l4) ^ s7;
      bf16x8 af[4], bfr[4];
      #pragma unroll
      for (int mi = 0; mi < 4; ++mi)
        af[mi]  = *(const bf16x8*)&curA[((wm << 6) + (mi << 4) + l15) * 64 + (ch << 3)];
      #pragma unroll
      for (int nj = 0; nj < 4; ++nj)
        bfr[nj] = *(const bf16x8*)&curB[((wn << 6) + (nj << 4) + l15) * 64 + (ch << 3)];
      __builtin_amdgcn_s_setprio(1);
      #pragma unroll
      for (int mi = 0; mi < 4; ++mi)
        #pragma unroll
        for (int nj = 0; nj < 4; ++nj)
          acc[mi][nj] = __builtin_amdgcn_mfma_f32_16x16x32_bf16(af[mi], bfr[nj], acc[mi][nj], 0, 0, 0);
      __builtin_amdgcn_s_setprio(0);
    }
    asm volatile("" ::: "memory");
    bufR = (bufR == 2) ? 0 : bufR + 1;
  }
#undef STG_A
#undef STG_B

  #pragma unroll
  for (int mi = 0; mi < 4; ++mi)
    #pragma unroll
    for (int nj = 0; nj < 4; ++nj) {
      const int row = mBase + (wm << 6) + (mi << 4) + (l4 << 2);
      const int col = nBase + (wn << 6) + (nj << 4) + l15;
      #pragma unroll
      for (int r = 0; r < 4; ++r) {
        float v = acc[mi][nj][r];
        if (OUT_F32) ((float*)Cv)[(size_t)(row + r) * N + col] = v;
        else ((unsigned short*)Cv)[(size_t)(row + r) * N + col] = f2bf(v);
      }
    }
}

// ---------------- V transpose (unchanged) ----------------------------------------
__global__ void vtrans_kernel(const unsigned short* __restrict__ qkv, unsigned short* __restrict__ vt) {
  const int bh = blockIdx.y;
  const int b = bh >> 4, h = bh & 15;
  const int t0 = blockIdx.x << 6;
  __shared__ unsigned short tile[64][65];
  const int tid = threadIdx.x;
  const unsigned short* src = qkv + (size_t)b * Tx * 3072 + 2048 + h * 64;
  for (int e = tid; e < 4096; e += 256) {
    int r = e >> 6, c = e & 63;
    tile[c][r] = src[(size_t)(t0 + r) * 3072 + c];
  }
  __syncthreads();
  unsigned short* dst = vt + (size_t)bh * 64 * Tx + t0;
  for (int e = tid; e < 4096; e += 256) {
    int d = e >> 6, tt = e & 63;
    dst[(size_t)d * Tx + tt] = tile[d][tt];
  }
}

// ---------------- causal flash attention v4: swapped QK^T -------------------------
// s = mfma(K,Q) -> lane holds S[q = l15][kv = kv0 + nt*16 + l4*4 + r]: 4 consecutive
// kv per (lane,nt) -> P-write = 8 cvt_pk + 4 ds_write_b64. m/rs scalar per lane
// (q = l15), uniform across the 4 l4-lanes of a q-row. Scale folded into exp2 fma.
// PV and O layout unchanged (O q-axis = l4*4+r -> corr/rs need a 4-shfl transpose).
__device__ __forceinline__ void compute_half(
    const unsigned short* __restrict__ Ks, const unsigned short* __restrict__ Vs,
    unsigned short* __restrict__ Plw,
    bf16x8 aq0, bf16x8 aq1, float& m_run, float& rs, f32x4* oacc,
    int qrow0, int kv0, bool diag, int l15, int l4)
{
  const float SC = 0.125f * 1.44269504f;   // (1/sqrt(64)) * log2(e)
  f32x4 s[4];
  #pragma unroll
  for (int nt = 0; nt < 4; ++nt) { s[nt][0]=0.f; s[nt][1]=0.f; s[nt][2]=0.f; s[nt][3]=0.f; }
  #pragma unroll
  for (int nt = 0; nt < 4; ++nt) {
    const int r = (nt << 4) + l15, sz = r & 7;
    bf16x8 bk0 = *(const bf16x8*)&Ks[r * 64 + ((l4 ^ sz) << 3)];
    bf16x8 bk1 = *(const bf16x8*)&Ks[r * 64 + (((l4 + 4) ^ sz) << 3)];
    s[nt] = __builtin_amdgcn_mfma_f32_16x16x32_bf16(bk0, aq0, s[nt], 0, 0, 0);
    s[nt] = __builtin_amdgcn_mfma_f32_16x16x32_bf16(bk1, aq1, s[nt], 0, 0, 0);
  }
  if (diag) {
    const int q = qrow0 + l15;
    #pragma unroll
    for (int nt = 0; nt < 4; ++nt) {
      const int kvb = kv0 + (nt << 4) + (l4 << 2);
      #pragma unroll
      for (int r = 0; r < 4; ++r)
        if (kvb + r > q) s[nt][r] = -3.0e38f;
    }
  }
  // in-lane max of 16 raw logits
  float pm = fmaxf(fmaxf(fmaxf(s[0][0],s[0][1]),fmaxf(s[0][2],s[0][3])),
                   fmaxf(fmaxf(s[1][0],s[1][1]),fmaxf(s[1][2],s[1][3])));
  pm = fmaxf(pm, fmaxf(fmaxf(fmaxf(s[2][0],s[2][1]),fmaxf(s[2][2],s[2][3])),
                       fmaxf(fmaxf(s[3][0],s[3][1]),fmaxf(s[3][2],s[3][3]))));
  const float DEFER = 44.36142f;           // 8 exp2-units / SC, raw-logit units
  if (!__all(pm <= m_run + DEFER)) {       // rare fallback
    pm = fmaxf(pm, __shfl_xor(pm, 16));
    pm = fmaxf(pm, __shfl_xor(pm, 32));    // max across the 4 lanes sharing q=l15
    const float mnew = fmaxf(m_run, pm);
    const float corr = exp2f((m_run - mnew) * SC);
    rs *= corr;
    float corrT[4];
    #pragma unroll
    for (int r = 0; r < 4; ++r) corrT[r] = __shfl(corr, (l4 << 2) + r);
    #pragma unroll
    for (int nt = 0; nt < 4; ++nt)
      #pragma unroll
      for (int r = 0; r < 4; ++r) oacc[nt][r] *= corrT[r];
    m_run = mnew;
  }
  const float msc = m_run * SC;
  float lsum = 0.f;
  #pragma unroll
  for (int nt = 0; nt < 4; ++nt)
    #pragma unroll
    for (int r = 0; r < 4; ++r) {
      float p = exp2f(__builtin_fmaf(s[nt][r], SC, -msc));
      s[nt][r] = p;
      lsum += p;
    }
  rs += lsum;
  // P -> LDS: packed pairs, row q=l15, cols nt*16 + l4*4 + (0..3)
  #pragma unroll
  for (int nt = 0; nt < 4; ++nt) {
    uint2 u;
    u.x = cvt_pk_bf16(s[nt][0], s[nt][1]);
    u.y = cvt_pk_bf16(s[nt][2], s[nt][3]);
    *(uint2*)&Plw[l15 * 72 + (nt << 4) + (l4 << 2)] = u;
  }
  asm volatile("s_waitcnt lgkmcnt(0)" ::: "memory");
  __builtin_amdgcn_sched_barrier(0);
  bf16x8 ap0 = *(const bf16x8*)&Plw[l15 * 72 + (l4 << 3)];
  bf16x8 ap1 = *(const bf16x8*)&Plw[l15 * 72 + 32 + (l4 << 3)];
  #pragma unroll
  for (int nt = 0; nt < 4; ++nt) {
    const int r = (nt << 4) + l15, vz = r & 7;
    bf16x8 bv0 = *(const bf16x8*)&Vs[r * 64 + ((l4 ^ vz) << 3)];
    bf16x8 bv1 = *(const bf16x8*)&Vs[r * 64 + (((l4 + 4) ^ vz) << 3)];
    oacc[nt] = __builtin_amdgcn_mfma_f32_16x16x32_bf16(ap0, bv0, oacc[nt], 0, 0, 0);
    oacc[nt] = __builtin_amdgcn_mfma_f32_16x16x32_bf16(ap1, bv1, oacc[nt], 0, 0, 0);
  }
}

__global__ __launch_bounds__(256, 4) void attn_kernel(const unsigned short* __restrict__ qkv,
                                                      const unsigned short* __restrict__ vt,
                                                      unsigned short* __restrict__ aout)
{
  const int id = blockIdx.x;
  const int xcd = id & 7, sblk = id >> 3;
  const int xblk = sblk & 15;
  const int bh = (xcd << 3) + (sblk >> 4);
  const int b = bh >> 4, h = bh & 15;
  const int wave = threadIdx.x >> 6, lane = threadIdx.x & 63;
  const int l15 = lane & 15, l4 = lane >> 4;
  const int qi0 = (xblk << 2) + wave;

  const unsigned short* qp = qkv + (size_t)b * Tx * 3072 + h * 64;
  const unsigned short* kp = qp + 1024;
  const unsigned short* vp = vt + (size_t)bh * 64 * Tx;
  unsigned short* op = aout + (size_t)b * Tx * 1024 + h * 64;

  __shared__ unsigned short Ks[64 * 64];
  __shared__ unsigned short Vs[64 * 64];
  __shared__ unsigned short Pl[4][2][16 * 72];

  const int qiA = qi0, qiB = 127 - qi0;
  const int qrA = qiA << 4, qrB = qiB << 4;
  const int lastA = xblk, lastB = 31 - xblk;

  bf16x8 aqA0 = *(const bf16x8*)&qp[(size_t)(qrA + l15) * 3072 + (l4 << 3)];
  bf16x8 aqA1 = *(const bf16x8*)&qp[(size_t)(qrA + l15) * 3072 + 32 + (l4 << 3)];
  bf16x8 aqB0 = *(const bf16x8*)&qp[(size_t)(qrB + l15) * 3072 + (l4 << 3)];
  bf16x8 aqB1 = *(const bf16x8*)&qp[(size_t)(qrB + l15) * 3072 + 32 + (l4 << 3)];

  float mA = 0.f, rsA = 0.f, mB = 0.f, rsB = 0.f;
  f32x4 oA[4], oB[4];
  #pragma unroll
  for (int nt = 0; nt < 4; ++nt) {
    oA[nt][0]=0.f; oA[nt][1]=0.f; oA[nt][2]=0.f; oA[nt][3]=0.f;
    oB[nt][0]=0.f; oB[nt][1]=0.f; oB[nt][2]=0.f; oB[nt][3]=0.f;
  }

  const int srw = lane >> 3;
  const int sj  = (lane & 7) ^ srw;

  for (int kvt = 0; kvt <= lastB; ++kvt) {
    const int kv0 = kvt << 6;
    {
      const int c0 = wave << 1, c1 = c0 + 1;
      const int r0 = (c0 << 3) + srw, r1 = (c1 << 3) + srw;
      GLOAD_LDS16(kp + (size_t)(kv0 + r0) * 3072 + (sj << 3), Ks + (c0 << 9));
      GLOAD_LDS16(kp + (size_t)(kv0 + r1) * 3072 + (sj << 3), Ks + (c1 << 9));
      GLOAD_LDS16(vp + (size_t)r0 * 2048 + kv0 + (sj << 3),   Vs + (c0 << 9));
      GLOAD_LDS16(vp + (size_t)r1 * 2048 + kv0 + (sj << 3),   Vs + (c1 << 9));
    }
    __syncthreads();

    compute_half(Ks, Vs, Pl[wave][1], aqB0, aqB1, mB, rsB, oB, qrB, kv0, kvt == lastB, l15, l4);
    if (kvt <= lastA)
      compute_half(Ks, Vs, Pl[wave][0], aqA0, aqA1, mA, rsA, oA, qrA, kv0, kvt == lastA, l15, l4);

    __syncthreads();
  }

  // rs lives per q=l15 (partial per l4-lane): complete the sum, then transpose to
  // the O layout's q-axis (l4*4+r) via shfl.
  rsA += __shfl_xor(rsA, 16); rsA += __shfl_xor(rsA, 32);
  rsB += __shfl_xor(rsB, 16); rsB += __shfl_xor(rsB, 32);
  #pragma unroll
  for (int r = 0; r < 4; ++r) {
    const float invA = 1.0f / __shfl(rsA, (l4 << 2) + r);
    const float invB = 1.0f / __shfl(rsB, (l4 << 2) + r);
    #pragma unroll
    for (int nt = 0; nt < 4; ++nt) {
      op[(size_t)(qrA + (l4 << 2) + r) * 1024 + (nt << 4) + l15] = f2bf(oA[nt][r] * invA);
      op[(size_t)(qrB + (l4 << 2) + r) * 1024 + (nt << 4) + l15] = f2bf(oB[nt][r] * invB);
    }
  }
}

// ---------------- launch ----------------------------------------------------------
extern "C" void kernel_launch(void* const* d_in, const int* in_sizes, int n_in,
                              void* d_out, int out_size, void* d_ws, size_t ws_size,
                              hipStream_t stream) {
  const float* x     = (const float*)d_in[0];
  const float* wqkv  = (const float*)d_in[1];
  const float* wproj = (const float*)d_in[2];

  char* ws = (char*)d_ws;
  unsigned short* qkvb = (unsigned short*)(ws);
  unsigned short* vtb  = (unsigned short*)(ws + 50331648);
  unsigned short* xb   = (unsigned short*)(ws + 50331648 + 16777216);
  unsigned short* wqb  = (unsigned short*)(ws + 50331648 + 16777216 + 16777216);
  unsigned short* wpb  = (unsigned short*)(ws + 50331648 + 16777216 + 16777216 + 6291456);
  unsigned short* aob  = xb;  // alias: xb dead after GEMM1

  cvt3_kernel<<<6144, 256, 0, stream>>>(x, wqkv, wproj, xb, wqb, wpb);

  gemm8p<0><<<dim3(768), 512, 0, stream>>>(xb, wqb, qkvb, Mx, 3072, 1024);
  vtrans_kernel<<<dim3(32, 64), 256, 0, stream>>>(qkvb, vtb);
  attn_kernel<<<1024, 256, 0, stream>>>(qkvb, vtb, aob);
  gemm8p<1><<<dim3(256), 512, 0, stream>>>(aob, wpb, d_out, Mx, 1024, 1024);
}